// Round 10
// baseline (524.716 us; speedup 1.0000x reference)
//
#include <hip/hip_runtime.h>

typedef __attribute__((ext_vector_type(8))) short bf16x8;
typedef __attribute__((ext_vector_type(16))) float f32x16;
typedef unsigned short u16;
typedef unsigned int u32;
typedef long i64;
typedef unsigned char u8;

#define NN 1024
#define ETOT 523776
#define EPSV 1e-5f

// LDS layout (bytes)
#define L_PSUM 0      /* 64*17*4 = 4352 */
#define L_PSQ  4352   /* 4352 */
#define L_SSC  8704   /* 256 */
#define L_SSM  8960   /* 256 */
#define L_B1   9216   /* 2048 */
#define L_G    11264  /* 1024 */
#define L_BB   12288  /* 1024 */
#define L_W3   13312  /* 1024 */
#define L_TILE 14336  /* 32 KiB: A1 chunk-major bf16 [kk16][hi2][e64][16B] aliased under
                         h1 chunk-major fp8  [kk32][hi2][e64][8B] */
#define L_TOTAL 47104 /* 3 blocks/CU: 141312 <= 163840 */

__device__ __forceinline__ u16 f2bf(float f) {
  union { float f; u32 u; } v; v.f = f;
  u32 r = v.u + 0x7FFFu + ((v.u >> 16) & 1u);   // RNE, finite inputs only
  return (u16)(r >> 16);
}

// hardware packed f32x2 -> bf16x2 (RNE), low = a, high = b
__device__ __forceinline__ u32 cvtpk(float a, float b) {
  u32 r;
  asm("v_cvt_pk_bf16_f32 %0, %1, %2" : "=v"(r) : "v"(a), "v"(b));
  return r;
}

// ---- prep: W1^T [512][256] bf16 ; gamma-scaled W2^T [256][512] fp8 e4m3 ----
__global__ void prep_wt(const float* __restrict__ W1, const float* __restrict__ W2,
                        const float* __restrict__ gammav,
                        u16* __restrict__ W1t, u8* __restrict__ W2g8) {
  int idx = blockIdx.x * 256 + threadIdx.x;      // [0, 131072)
  { int n = idx >> 8, k = idx & 255; W1t[idx] = f2bf(W1[k*512 + n]); }
  { int o = idx >> 9, c = idx & 511;
    float v = gammav[c] * W2[c*256 + o];
    int p = __builtin_amdgcn_cvt_pk_fp8_f32(v, 0.f, 0, false);
    W2g8[idx] = (u8)(p & 0xff); }
}

// ---- prep: G[o] = sum_c gamma[c]*W2[c,o]; BB[o] = b2[o] + sum_c beta[c]*W2[c,o] ----
__global__ void prep_vec(const float* __restrict__ W2, const float* __restrict__ gammav,
                         const float* __restrict__ betav, const float* __restrict__ b2v,
                         float* __restrict__ Gv, float* __restrict__ BBv) {
  int o = blockIdx.x, t = threadIdx.x;           // 256 blocks x 64 threads
  float g = 0.f, bb = 0.f;
  for (int c = t; c < 512; c += 64) {
    float w = W2[c*256 + o];
    g  += gammav[c] * w;
    bb += betav[c]  * w;
  }
  #pragma unroll
  for (int off = 1; off < 64; off <<= 1) {
    g  += __shfl_xor(g,  off, 64);
    bb += __shfl_xor(bb, off, 64);
  }
  if (t == 0) { Gv[o] = g; BBv[o] = bb + b2v[o]; }
}

// ---- main fused kernel: one block = 8x8 node tile = 64 edges; swapped GEMMs ----
__launch_bounds__(512, 4)
__global__ void edge_main(const float* __restrict__ emb,
                          const float* __restrict__ b1v,
                          const float* __restrict__ b3v,
                          const float* __restrict__ w3v,
                          const float* __restrict__ Gv,
                          const float* __restrict__ BBv,
                          const u16* __restrict__ W1t,
                          const u8* __restrict__ W2g8,
                          float* __restrict__ out) {
  extern __shared__ char smem[];
  float* psum = (float*)(smem + L_PSUM);         // [64][17]
  float* psq  = (float*)(smem + L_PSQ);          // [64][17]
  float* ssc  = (float*)(smem + L_SSC);
  float* ssm  = (float*)(smem + L_SSM);
  float* sb1  = (float*)(smem + L_B1);
  float* sG   = (float*)(smem + L_G);
  float* sBB  = (float*)(smem + L_BB);
  float* sw3  = (float*)(smem + L_W3);
  char*  tile = smem + L_TILE;

  const int tid  = threadIdx.x;
  const int wave = tid >> 6;
  const int lane = tid & 63;
  const int l31  = lane & 31;
  const int hi   = lane >> 5;

  // exact upper-triangle (incl. diagonal) tile mapping: 8256 blocks
  int kblk = blockIdx.x;
  int bi = (int)((257.0f - sqrtf(66049.0f - 8.0f*(float)kblk)) * 0.5f);
  bi = bi < 0 ? 0 : (bi > 127 ? 127 : bi);
  while (bi*128 - bi*(bi-1)/2 > kblk) --bi;
  while ((bi+1)*128 - (bi+1)*bi/2 <= kblk) ++bi;
  const int bj = bi + (kblk - (bi*128 - bi*(bi-1)/2));
  const int i0 = bi*8, j0 = bj*8;

  // ---- stage A1 = [e_i - e_j | e_i * e_j] bf16, chunk-major [kk][hi][e][16B] ----
  {
    const int trow = tid >> 3, cg = tid & 7;     // edge row, col-group (16 dims)
    const int sa = trow >> 3, sb = trow & 7;
    const float4* pei = (const float4*)(emb + (i0 + sa)*128 + cg*16);
    const float4* pej = (const float4*)(emb + (j0 + sb)*128 + cg*16);
    float4 eA0 = pei[0], eA1 = pei[1], eA2 = pei[2], eA3 = pei[3];
    float4 eB0 = pej[0], eB1 = pej[1], eB2 = pej[2], eB3 = pej[3];
    char* base = tile + trow*16;
    uint4 v;
    // diff, k-chunk kk=cg: hi=0 (dims cg*16..+7), hi=1 (dims +8..15)
    v.x = cvtpk(eA0.x-eB0.x, eA0.y-eB0.y); v.y = cvtpk(eA0.z-eB0.z, eA0.w-eB0.w);
    v.z = cvtpk(eA1.x-eB1.x, eA1.y-eB1.y); v.w = cvtpk(eA1.z-eB1.z, eA1.w-eB1.w);
    *(uint4*)(base + cg*2048) = v;
    v.x = cvtpk(eA2.x-eB2.x, eA2.y-eB2.y); v.y = cvtpk(eA2.z-eB2.z, eA2.w-eB2.w);
    v.z = cvtpk(eA3.x-eB3.x, eA3.y-eB3.y); v.w = cvtpk(eA3.z-eB3.z, eA3.w-eB3.w);
    *(uint4*)(base + cg*2048 + 1024) = v;
    // prod, k-chunk kk=8+cg
    v.x = cvtpk(eA0.x*eB0.x, eA0.y*eB0.y); v.y = cvtpk(eA0.z*eB0.z, eA0.w*eB0.w);
    v.z = cvtpk(eA1.x*eB1.x, eA1.y*eB1.y); v.w = cvtpk(eA1.z*eB1.z, eA1.w*eB1.w);
    *(uint4*)(base + (8+cg)*2048) = v;
    v.x = cvtpk(eA2.x*eB2.x, eA2.y*eB2.y); v.y = cvtpk(eA2.z*eB2.z, eA2.w*eB2.w);
    v.z = cvtpk(eA3.x*eB3.x, eA3.y*eB3.y); v.w = cvtpk(eA3.z*eB3.z, eA3.w*eB3.w);
    *(uint4*)(base + (8+cg)*2048 + 1024) = v;
  }
  sb1[tid] = b1v[tid];
  if (tid < 256) { sG[tid] = Gv[tid]; sBB[tid] = BBv[tid]; sw3[tid] = w3v[tid]; }
  __syncthreads();                               // B0

  f32x16 zero16;
  #pragma unroll
  for (int i = 0; i < 16; ++i) zero16[i] = 0.f;

  // ---- GEMM1 (swapped): h1^T[c][e] = W1^T x A1^T; wave owns 64 c ----
  f32x16 acc00 = zero16, acc01 = zero16, acc10 = zero16, acc11 = zero16;
  {
    const u16* w1p = W1t + (wave*64 + l31)*256 + hi*8;
    const char* a1p = tile + hi*1024 + l31*16;
    #pragma unroll
    for (int kk = 0; kk < 16; ++kk) {
      bf16x8 a0 = *(const bf16x8*)(w1p + kk*16);
      bf16x8 a1 = *(const bf16x8*)(w1p + 8192 + kk*16);
      bf16x8 b0 = *(const bf16x8*)(a1p + kk*2048);          // edge l31
      bf16x8 b1 = *(const bf16x8*)(a1p + kk*2048 + 512);    // edge l31+32
      acc00 = __builtin_amdgcn_mfma_f32_32x32x16_bf16(a0, b0, acc00, 0, 0, 0);
      acc01 = __builtin_amdgcn_mfma_f32_32x32x16_bf16(a0, b1, acc01, 0, 0, 0);
      acc10 = __builtin_amdgcn_mfma_f32_32x32x16_bf16(a1, b0, acc10, 0, 0, 0);
      acc11 = __builtin_amdgcn_mfma_f32_32x32x16_bf16(a1, b1, acc11, 0, 0, 0);
    }
  }
  __syncthreads();                               // B1: A1 reads done (h1 may overwrite)

  // ---- +b1, relu -> h1 fp8 chunk-major [kk][hi][e][8B] + in-lane LN stats ----
  {
    float sum0 = 0.f, sq0 = 0.f, sum1 = 0.f, sq1 = 0.f;
    char* h1r0 = tile + l31*8;                   // edge l31
    char* h1r1 = tile + l31*8 + 256;             // edge l31+32
    auto h1pass = [&](const f32x16& A0, const f32x16& A1v, int mbase) {
      #pragma unroll
      for (int rg = 0; rg < 16; rg += 4) {
        const int cbase = mbase + (rg >> 2)*8 + hi*4;      // 4 consecutive c
        const int coff  = (cbase >> 4)*1024 + ((cbase >> 3)&1)*512 + (cbase & 7);
        const float ba = sb1[cbase+0], bbv = sb1[cbase+1],
                    bc = sb1[cbase+2], bd = sb1[cbase+3];
        float v0 = fmaxf(A0[rg+0] + ba, 0.f);
        float v1 = fmaxf(A0[rg+1] + bbv, 0.f);
        float v2 = fmaxf(A0[rg+2] + bc, 0.f);
        float v3 = fmaxf(A0[rg+3] + bd, 0.f);
        int p = __builtin_amdgcn_cvt_pk_fp8_f32(v0, v1, 0, false);
        p = __builtin_amdgcn_cvt_pk_fp8_f32(v2, v3, p, true);
        *(u32*)(h1r0 + coff) = (u32)p;
        sum0 += (v0 + v1) + (v2 + v3);
        sq0 = fmaf(v0,v0, sq0); sq0 = fmaf(v1,v1, sq0);
        sq0 = fmaf(v2,v2, sq0); sq0 = fmaf(v3,v3, sq0);
        float w0 = fmaxf(A1v[rg+0] + ba, 0.f);
        float w1 = fmaxf(A1v[rg+1] + bbv, 0.f);
        float w2 = fmaxf(A1v[rg+2] + bc, 0.f);
        float w3_ = fmaxf(A1v[rg+3] + bd, 0.f);
        int q = __builtin_amdgcn_cvt_pk_fp8_f32(w0, w1, 0, false);
        q = __builtin_amdgcn_cvt_pk_fp8_f32(w2, w3_, q, true);
        *(u32*)(h1r1 + coff) = (u32)q;
        sum1 += (w0 + w1) + (w2 + w3_);
        sq1 = fmaf(w0,w0, sq1); sq1 = fmaf(w1,w1, sq1);
        sq1 = fmaf(w2,w2, sq1); sq1 = fmaf(w3_,w3_, sq1);
      }
    };
    h1pass(acc00, acc01, wave*64);
    h1pass(acc10, acc11, wave*64 + 32);
    const int pc = wave*2 + hi;
    psum[l31*17 + pc]        = sum0;
    psq [l31*17 + pc]        = sq0;
    psum[(l31 + 32)*17 + pc] = sum1;
    psq [(l31 + 32)*17 + pc] = sq1;
  }
  __syncthreads();                               // B2: h1 + partials visible

  // ---- stats (wave0) overlapped with GEMM2 (all waves) ----
  if (tid < 64) {
    float s = 0.f, ss = 0.f;
    #pragma unroll
    for (int k = 0; k < 16; ++k) { s += psum[tid*17 + k]; ss += psq[tid*17 + k]; }
    float mu  = s * (1.f/512.f);
    float var = ss * (1.f/512.f) - mu*mu;
    float sc  = rsqrtf(var + EPSV);
    ssc[tid] = sc;
    ssm[tid] = mu * sc;
  }

  // ---- GEMM2 (swapped, fp8): out2^T[o][e] = W2g^T x h1^T; wave owns 32 o ----
  f32x16 acc20 = zero16, acc21 = zero16;
  {
    const i64* w2p = (const i64*)(W2g8 + (wave*32 + l31)*512 + hi*8);
    const char* h0p = tile + hi*512 + l31*8;
    #pragma unroll 8
    for (int kk = 0; kk < 32; ++kk) {
      i64 a  = w2p[kk*2];
      i64 b0 = *(const i64*)(h0p + kk*1024);
      i64 b1 = *(const i64*)(h0p + kk*1024 + 256);
      acc20 = __builtin_amdgcn_mfma_f32_32x32x16_fp8_fp8(a, b0, acc20, 0, 0, 0);
      acc21 = __builtin_amdgcn_mfma_f32_32x32x16_fp8_fp8(a, b1, acc21, 0, 0, 0);
    }
  }
  __syncthreads();                               // B3: stats visible

  // ---- epilogue2: LN-affine + relu + W3 dot, fully in-lane ----
  {
    const float scA = ssc[l31],      smA = ssm[l31];
    const float scB = ssc[l31 + 32], smB = ssm[l31 + 32];
    float part0 = 0.f, part1 = 0.f;
    #pragma unroll
    for (int rg = 0; rg < 16; ++rg) {
      const int o = wave*32 + (rg & 3) + 8*(rg >> 2) + 4*hi;
      const float g = sG[o], bb = sBB[o], w3 = sw3[o];
      float t0 = fmaxf(fmaf(scA, acc20[rg], fmaf(-smA, g, bb)), 0.f);
      part0 = fmaf(t0, w3, part0);
      float t1 = fmaxf(fmaf(scB, acc21[rg], fmaf(-smB, g, bb)), 0.f);
      part1 = fmaf(t1, w3, part1);
    }
    const int pc = wave*2 + hi;
    psum[l31*17 + pc]        = part0;
    psum[(l31 + 32)*17 + pc] = part1;
  }
  __syncthreads();                               // B4: psum ready

  // ---- flush logits + pairs ----
  if (tid < 64) {
    float s = 0.f;
    #pragma unroll
    for (int k = 0; k < 16; ++k) s += psum[tid*17 + k];
    float logit = s + b3v[0];
    int a = tid >> 3, b = tid & 7;
    int i = i0 + a, j = j0 + b;
    if (i < j) {
      int e = i*(2*NN - i - 1)/2 + (j - i - 1);
      out[e] = logit;
      out[ETOT + 2*e]     = (float)i;
      out[ETOT + 2*e + 1] = (float)j;
    }
  }
}

extern "C" void kernel_launch(void* const* d_in, const int* in_sizes, int n_in,
                              void* d_out, int out_size, void* d_ws, size_t ws_size,
                              hipStream_t stream) {
  const float* emb   = (const float*)d_in[0];
  const float* W1    = (const float*)d_in[1];
  const float* b1    = (const float*)d_in[2];
  const float* gamma = (const float*)d_in[3];
  const float* beta  = (const float*)d_in[4];
  const float* W2    = (const float*)d_in[5];
  const float* b2    = (const float*)d_in[6];
  const float* W3    = (const float*)d_in[7];
  const float* b3    = (const float*)d_in[8];

  char* ws   = (char*)d_ws;
  u16*  W1t  = (u16*)ws;                          // 256 KiB
  u8*   W2g8 = (u8*)(ws + 512*256*2);             // 128 KiB
  float* Gv  = (float*)(ws + 512*256*2 + 256*512);        // 1 KiB
  float* BBv = (float*)(ws + 512*256*2 + 256*512 + 1024); // 1 KiB

  (void)hipFuncSetAttribute((const void*)edge_main,
                            hipFuncAttributeMaxDynamicSharedMemorySize, L_TOTAL);

  prep_wt<<<512, 256, 0, stream>>>(W1, W2, gamma, W1t, W2g8);
  prep_vec<<<256, 64, 0, stream>>>(W2, gamma, beta, b2, Gv, BBv);
  edge_main<<<8256, 512, L_TOTAL, stream>>>(emb, b1, b3, W3, Gv, BBv,
                                            W1t, W2g8, (float*)d_out);
}

// Round 11
// 276.206 us; speedup vs baseline: 1.8997x; 1.8997x over previous
//
#include <hip/hip_runtime.h>

typedef __attribute__((ext_vector_type(16))) float f32x16;
typedef unsigned short u16;
typedef unsigned int u32;
typedef unsigned char u8;
typedef long i64;

#define NN 1024
#define ETOT 523776
#define EPSV 1e-5f

// LDS layout (bytes)
#define L_PSUM 0      /* [64][4] f32 = 1024 */
#define L_PSQ  1024   /* 1024 */
#define L_EB1  2048   /* b1 f32[512] (h1-pass) -> reused for epi partials [64][4] */
#define L_G    4096   /* 1024 */
#define L_BB   5120   /* 1024 */
#define L_W3   6144   /* 1024 */
#define L_TILE 7168   /* 32 KiB: h1 fp8 phys slots; A1 fp8 16K aliased at +16384 */
#define L_TOTAL 39936 /* x4 blocks = 159744 <= 163840 */

// scales: A1 x4, W1 x64 (G1 acc /256); h1 x16, W2g x64 (G2 acc /1024)
#define INV_G1 0.00390625f
#define INV_G2 0.0009765625f

__device__ __forceinline__ u32 pk4fp8(float a, float b, float c, float d) {
  int p = __builtin_amdgcn_cvt_pk_fp8_f32(a, b, 0, false);
  p = __builtin_amdgcn_cvt_pk_fp8_f32(c, d, p, true);
  return (u32)p;
}

// ---- prep: W1 -> fragment-major fp8 x64 ; W2*gamma -> fragment-major fp8 x64 ----
__global__ void prep_w(const float* __restrict__ W1, const float* __restrict__ W2,
                       const float* __restrict__ gammav,
                       u8* __restrict__ W1f, u8* __restrict__ W2f) {
  int idx = blockIdx.x*256 + threadIdx.x;        // [0, 131072)
  int a = idx >> 8, b = idx & 255;               // a in [0,512), b in [0,256)
  {
    // W1f element (c=a, k=b): [c>>5][k>>4][ (k>>3)&1 ][c&31][k&7]
    float v = W1[b*512 + a] * 64.f;
    int p = __builtin_amdgcn_cvt_pk_fp8_f32(v, 0.f, 0, false);
    W1f[(a>>5)*8192 + (b>>4)*512 + ((b>>3)&1)*256 + (a&31)*8 + (b&7)] = (u8)(p & 0xff);
  }
  {
    // W2f element (c=a, o=b): [o>>5][c>>4][(c>>3)&1][o&31][c&7]
    float v = gammav[a] * W2[a*256 + b] * 64.f;
    int p = __builtin_amdgcn_cvt_pk_fp8_f32(v, 0.f, 0, false);
    W2f[(b>>5)*16384 + (a>>4)*512 + ((a>>3)&1)*256 + (b&31)*8 + (a&7)] = (u8)(p & 0xff);
  }
}

// ---- prep: G[o] = sum_c gamma[c]*W2[c,o]; BB[o] = b2[o] + sum_c beta[c]*W2[c,o] ----
__global__ void prep_vec(const float* __restrict__ W2, const float* __restrict__ gammav,
                         const float* __restrict__ betav, const float* __restrict__ b2v,
                         float* __restrict__ Gv, float* __restrict__ BBv) {
  int o = blockIdx.x, t = threadIdx.x;
  float g = 0.f, bb = 0.f;
  for (int c = t; c < 512; c += 64) {
    float w = W2[c*256 + o];
    g  += gammav[c] * w;
    bb += betav[c]  * w;
  }
  #pragma unroll
  for (int off = 1; off < 64; off <<= 1) {
    g  += __shfl_xor(g,  off, 64);
    bb += __shfl_xor(bb, off, 64);
  }
  if (t == 0) { Gv[o] = g; BBv[o] = bb + b2v[o]; }
}

// ---- main: 256-thread (4-wave) block = 8x8 node tile = 64 edges; all-fp8 swapped GEMMs ----
__launch_bounds__(256, 4)
__global__ void edge_main(const float* __restrict__ emb,
                          const float* __restrict__ b1v,
                          const float* __restrict__ b3v,
                          const float* __restrict__ w3v,
                          const float* __restrict__ Gv,
                          const float* __restrict__ BBv,
                          const u8* __restrict__ W1f,
                          const u8* __restrict__ W2f,
                          float* __restrict__ out) {
  extern __shared__ char smem[];
  float* psum = (float*)(smem + L_PSUM);
  float* psq  = (float*)(smem + L_PSQ);
  float* sb1  = (float*)(smem + L_EB1);          // b1, later epi partials
  float* sG   = (float*)(smem + L_G);
  float* sBB  = (float*)(smem + L_BB);
  float* sw3  = (float*)(smem + L_W3);
  char*  tile = smem + L_TILE;
  char*  A1   = tile + 16384;                    // aliased under h1 upper half

  const int tid  = threadIdx.x;
  const int w    = tid >> 6;                     // wave 0..3
  const int lane = tid & 63;
  const int l31  = lane & 31;
  const int hi   = lane >> 5;

  // exact upper-triangle tile mapping: 8256 blocks
  int kblk = blockIdx.x;
  int bi = (int)((257.0f - sqrtf(66049.0f - 8.0f*(float)kblk)) * 0.5f);
  bi = bi < 0 ? 0 : (bi > 127 ? 127 : bi);
  while (bi*128 - bi*(bi-1)/2 > kblk) --bi;
  while ((bi+1)*128 - (bi+1)*bi/2 <= kblk) ++bi;
  const int bj = bi + (kblk - (bi*128 - bi*(bi-1)/2));
  const int i0 = bi*8, j0 = bj*8;

  // ---- stage A1 fp8 (x4): [kk16][hi2][e64 ^ swz][8B]; wave = quarter (uniform) ----
  {
    const int e  = tid & 63;                     // edge row
    const int sa = e >> 3, sb = e & 7;
    const int f0 = (w & 1) * 64;                 // feature base
    const float4* pei = (const float4*)(emb + (i0 + sa)*128 + f0);
    const float4* pej = (const float4*)(emb + (j0 + sb)*128 + f0);
    #pragma unroll
    for (int q = 0; q < 4; ++q) {
      float4 x0 = pei[q*4+0], x1 = pei[q*4+1], x2 = pei[q*4+2], x3 = pei[q*4+3];
      float4 y0 = pej[q*4+0], y1 = pej[q*4+1], y2 = pej[q*4+2], y3 = pej[q*4+3];
      uint2 lo, hi2;
      if (w < 2) {
        lo.x  = pk4fp8((x0.x-y0.x)*4.f, (x0.y-y0.y)*4.f, (x0.z-y0.z)*4.f, (x0.w-y0.w)*4.f);
        lo.y  = pk4fp8((x1.x-y1.x)*4.f, (x1.y-y1.y)*4.f, (x1.z-y1.z)*4.f, (x1.w-y1.w)*4.f);
        hi2.x = pk4fp8((x2.x-y2.x)*4.f, (x2.y-y2.y)*4.f, (x2.z-y2.z)*4.f, (x2.w-y2.w)*4.f);
        hi2.y = pk4fp8((x3.x-y3.x)*4.f, (x3.y-y3.y)*4.f, (x3.z-y3.z)*4.f, (x3.w-y3.w)*4.f);
      } else {
        lo.x  = pk4fp8((x0.x*y0.x)*4.f, (x0.y*y0.y)*4.f, (x0.z*y0.z)*4.f, (x0.w*y0.w)*4.f);
        lo.y  = pk4fp8((x1.x*y1.x)*4.f, (x1.y*y1.y)*4.f, (x1.z*y1.z)*4.f, (x1.w*y1.w)*4.f);
        hi2.x = pk4fp8((x2.x*y2.x)*4.f, (x2.y*y2.y)*4.f, (x2.z*y2.z)*4.f, (x2.w*y2.w)*4.f);
        hi2.y = pk4fp8((x3.x*y3.x)*4.f, (x3.y*y3.y)*4.f, (x3.z*y3.z)*4.f, (x3.w*y3.w)*4.f);
      }
      char* base = A1 + (w*4 + q)*1024;
      *(uint2*)(base +       ((e*8) ^ (q << 5))) = lo;
      *(uint2*)(base + 512 + ((e*8) ^ (q << 5))) = hi2;
    }
  }
  sb1[tid] = b1v[tid]; sb1[tid + 256] = b1v[tid + 256];
  sG[tid] = Gv[tid]; sBB[tid] = BBv[tid]; sw3[tid] = w3v[tid];
  __syncthreads();                               // B0

  f32x16 z16;
  #pragma unroll
  for (int i = 0; i < 16; ++i) z16[i] = 0.f;

  float sum0 = 0.f, sq0 = 0.f, sum1 = 0.f, sq1 = 0.f;
  f32x16 A00, A01, A10, A11;

  const u8* w1p = W1f + (w*4)*8192 + hi*256 + l31*8;     // + ch*16384 + f*8192 + kk*512
  const char* a1rp = tile + 16384 + hi*512;              // + kk*1024 + swz-lane

  // h1-pass: +b1 (descale 1/256), relu, stats, fp8(x16) -> phys h1 slot
  auto h1pass = [&](int ch, const f32x16& F00, const f32x16& F01,
                    const f32x16& F10, const f32x16& F11) {
    #pragma unroll
    for (int f = 0; f < 2; ++f) {
      const f32x16& E0 = f ? F10 : F00;
      const f32x16& E1 = f ? F11 : F01;
      #pragma unroll
      for (int a = 0; a < 4; ++a) {
        const int c0 = w*128 + ch*64 + f*32 + a*8 + hi*4;
        const float b0 = sb1[c0+0], b1_ = sb1[c0+1], b2_ = sb1[c0+2], b3_ = sb1[c0+3];
        char* dst = tile + ch*16384 + (w*4 + f*2 + (a>>1))*1024 + (a&1)*512 + hi*4;
        {
          float v0 = fmaxf(fmaf(E0[a*4+0], INV_G1, b0), 0.f);
          float v1 = fmaxf(fmaf(E0[a*4+1], INV_G1, b1_), 0.f);
          float v2 = fmaxf(fmaf(E0[a*4+2], INV_G1, b2_), 0.f);
          float v3 = fmaxf(fmaf(E0[a*4+3], INV_G1, b3_), 0.f);
          *(u32*)(dst + l31*8) = pk4fp8(v0*16.f, v1*16.f, v2*16.f, v3*16.f);
          sum0 += (v0+v1)+(v2+v3);
          sq0 = fmaf(v0,v0,sq0); sq0 = fmaf(v1,v1,sq0);
          sq0 = fmaf(v2,v2,sq0); sq0 = fmaf(v3,v3,sq0);
        }
        {
          float v0 = fmaxf(fmaf(E1[a*4+0], INV_G1, b0), 0.f);
          float v1 = fmaxf(fmaf(E1[a*4+1], INV_G1, b1_), 0.f);
          float v2 = fmaxf(fmaf(E1[a*4+2], INV_G1, b2_), 0.f);
          float v3 = fmaxf(fmaf(E1[a*4+3], INV_G1, b3_), 0.f);
          *(u32*)(dst + (l31+32)*8) = pk4fp8(v0*16.f, v1*16.f, v2*16.f, v3*16.f);
          sum1 += (v0+v1)+(v2+v3);
          sq1 = fmaf(v0,v0,sq1); sq1 = fmaf(v1,v1,sq1);
          sq1 = fmaf(v2,v2,sq1); sq1 = fmaf(v3,v3,sq1);
        }
      }
    }
  };

  // ---- G1 chalf 0 (c = w*128 .. +64) ----
  A00 = z16; A01 = z16; A10 = z16; A11 = z16;
  #pragma unroll
  for (int kk = 0; kk < 16; ++kk) {
    i64 af0 = *(const i64*)(w1p + kk*512);
    i64 af1 = *(const i64*)(w1p + 8192 + kk*512);
    i64 bf0 = *(const i64*)(a1rp + kk*1024 + ((l31*8) ^ ((kk&3) << 5)));
    i64 bf1 = *(const i64*)(a1rp + kk*1024 + (((l31*8) ^ ((kk&3) << 5)) + 256));
    A00 = __builtin_amdgcn_mfma_f32_32x32x16_fp8_fp8(af0, bf0, A00, 0, 0, 0);
    A01 = __builtin_amdgcn_mfma_f32_32x32x16_fp8_fp8(af0, bf1, A01, 0, 0, 0);
    A10 = __builtin_amdgcn_mfma_f32_32x32x16_fp8_fp8(af1, bf0, A10, 0, 0, 0);
    A11 = __builtin_amdgcn_mfma_f32_32x32x16_fp8_fp8(af1, bf1, A11, 0, 0, 0);
  }
  h1pass(0, A00, A01, A10, A11);                 // writes lower 16K: no A1 overlap

  // ---- G1 chalf 1 (c = w*128+64 .. +128) ----
  A00 = z16; A01 = z16; A10 = z16; A11 = z16;
  #pragma unroll
  for (int kk = 0; kk < 16; ++kk) {
    i64 af0 = *(const i64*)(w1p + 16384 + kk*512);
    i64 af1 = *(const i64*)(w1p + 24576 + kk*512);
    i64 bf0 = *(const i64*)(a1rp + kk*1024 + ((l31*8) ^ ((kk&3) << 5)));
    i64 bf1 = *(const i64*)(a1rp + kk*1024 + (((l31*8) ^ ((kk&3) << 5)) + 256));
    A00 = __builtin_amdgcn_mfma_f32_32x32x16_fp8_fp8(af0, bf0, A00, 0, 0, 0);
    A01 = __builtin_amdgcn_mfma_f32_32x32x16_fp8_fp8(af0, bf1, A01, 0, 0, 0);
    A10 = __builtin_amdgcn_mfma_f32_32x32x16_fp8_fp8(af1, bf0, A10, 0, 0, 0);
    A11 = __builtin_amdgcn_mfma_f32_32x32x16_fp8_fp8(af1, bf1, A11, 0, 0, 0);
  }
  __syncthreads();                               // B1: all A1 reads done
  h1pass(1, A00, A01, A10, A11);                 // writes upper 16K (over A1)

  // per-wave LN partials: combine hi-halves, store [64][4]
  sum0 += __shfl_xor(sum0, 32, 64);  sq0 += __shfl_xor(sq0, 32, 64);
  sum1 += __shfl_xor(sum1, 32, 64);  sq1 += __shfl_xor(sq1, 32, 64);
  if (hi == 0) {
    psum[l31*4 + w] = sum0;       psq[l31*4 + w] = sq0;
    psum[(l31+32)*4 + w] = sum1;  psq[(l31+32)*4 + w] = sq1;
  }
  __syncthreads();                               // B2: h1 + partials visible

  // ---- in-lane stats for this lane's two edges ----
  float sc2A, smA, sc2B, smB;
  {
    float4 s = *(const float4*)(psum + l31*4);
    float4 q = *(const float4*)(psq  + l31*4);
    float su = (s.x+s.y)+(s.z+s.w), qu = (q.x+q.y)+(q.z+q.w);
    float mu = su * (1.f/512.f);
    float sc = rsqrtf(qu * (1.f/512.f) - mu*mu + EPSV);
    sc2A = sc * INV_G2; smA = mu * sc;
    s = *(const float4*)(psum + (l31+32)*4);
    q = *(const float4*)(psq  + (l31+32)*4);
    su = (s.x+s.y)+(s.z+s.w); qu = (q.x+q.y)+(q.z+q.w);
    mu = su * (1.f/512.f);
    sc = rsqrtf(qu * (1.f/512.f) - mu*mu + EPSV);
    sc2B = sc * INV_G2; smB = mu * sc;
  }

  // ---- G2: out2^T[o][e], wave owns o in [w*64, w*64+64) ----
  f32x16 C00 = z16, C01 = z16, C10 = z16, C11 = z16;
  {
    const u8* w2p = W2f + (w*2)*16384 + hi*256 + l31*8;
    const char* hrp = tile + hi*512 + l31*8;
    #pragma unroll
    for (int kk = 0; kk < 32; ++kk) {
      const int phys = (((kk>>2)&1) << 14) + (((kk&3) | ((kk>>3)<<2)) << 10);
      i64 a0 = *(const i64*)(w2p + kk*512);
      i64 a1 = *(const i64*)(w2p + 16384 + kk*512);
      i64 b0 = *(const i64*)(hrp + phys);
      i64 b1 = *(const i64*)(hrp + phys + 256);
      C00 = __builtin_amdgcn_mfma_f32_32x32x16_fp8_fp8(a0, b0, C00, 0, 0, 0);
      C01 = __builtin_amdgcn_mfma_f32_32x32x16_fp8_fp8(a0, b1, C01, 0, 0, 0);
      C10 = __builtin_amdgcn_mfma_f32_32x32x16_fp8_fp8(a1, b0, C10, 0, 0, 0);
      C11 = __builtin_amdgcn_mfma_f32_32x32x16_fp8_fp8(a1, b1, C11, 0, 0, 0);
    }
  }

  // ---- epilogue: LN-affine + relu + W3 dot (in-lane), partials -> sb1 region ----
  {
    float p0 = 0.f, p1 = 0.f;
    #pragma unroll
    for (int g = 0; g < 2; ++g) {
      const f32x16& E0 = g ? C10 : C00;
      const f32x16& E1 = g ? C11 : C01;
      #pragma unroll
      for (int rg = 0; rg < 16; ++rg) {
        const int o = w*64 + g*32 + (rg&3) + 8*(rg>>2) + 4*hi;
        const float gv = sG[o], bb = sBB[o], w3 = sw3[o];
        float t0 = fmaxf(fmaf(sc2A, E0[rg], fmaf(-smA, gv, bb)), 0.f);
        p0 = fmaf(t0, w3, p0);
        float t1 = fmaxf(fmaf(sc2B, E1[rg], fmaf(-smB, gv, bb)), 0.f);
        p1 = fmaf(t1, w3, p1);
      }
    }
    p0 += __shfl_xor(p0, 32, 64);
    p1 += __shfl_xor(p1, 32, 64);
    if (hi == 0) {                               // sb1 region: b1 reads all pre-B2 -> safe
      sb1[l31*4 + w] = p0;
      sb1[(l31+32)*4 + w] = p1;
    }
  }
  __syncthreads();                               // B3

  // ---- flush logits + pairs ----
  if (tid < 64) {
    float4 s = *(const float4*)(sb1 + tid*4);
    float logit = (s.x+s.y)+(s.z+s.w) + b3v[0];
    int a = tid >> 3, b = tid & 7;
    int i = i0 + a, j = j0 + b;
    if (i < j) {
      int e = i*(2*NN - i - 1)/2 + (j - i - 1);
      out[e] = logit;
      out[ETOT + 2*e]     = (float)i;
      out[ETOT + 2*e + 1] = (float)j;
    }
  }
}

extern "C" void kernel_launch(void* const* d_in, const int* in_sizes, int n_in,
                              void* d_out, int out_size, void* d_ws, size_t ws_size,
                              hipStream_t stream) {
  const float* emb   = (const float*)d_in[0];
  const float* W1    = (const float*)d_in[1];
  const float* b1    = (const float*)d_in[2];
  const float* gamma = (const float*)d_in[3];
  const float* beta  = (const float*)d_in[4];
  const float* W2    = (const float*)d_in[5];
  const float* b2    = (const float*)d_in[6];
  const float* W3    = (const float*)d_in[7];
  const float* b3    = (const float*)d_in[8];

  char* ws   = (char*)d_ws;
  u8*  W1f = (u8*)ws;                            // 128 KiB
  u8*  W2f = (u8*)(ws + 131072);                 // 128 KiB
  float* Gv  = (float*)(ws + 262144);            // 1 KiB
  float* BBv = (float*)(ws + 263168);            // 1 KiB

  (void)hipFuncSetAttribute((const void*)edge_main,
                            hipFuncAttributeMaxDynamicSharedMemorySize, L_TOTAL);

  prep_w<<<512, 256, 0, stream>>>(W1, W2, gamma, W1f, W2f);
  prep_vec<<<256, 64, 0, stream>>>(W2, gamma, beta, b2, Gv, BBv);
  edge_main<<<8256, 256, L_TOTAL, stream>>>(emb, b1, b3, W3, Gv, BBv,
                                            W1f, W2f, (float*)d_out);
}